// Round 1
// baseline (28828.790 us; speedup 1.0000x reference)
//
#include <hip/hip_runtime.h>

#define NB 32
#define NP 65536
#define NS 1024
#define NT 1024
#define PPT (NP / NT)   // 64 points per thread

__global__ __launch_bounds__(NT) void fps_kernel(const float* __restrict__ pts,
                                                 float* __restrict__ out) {
#pragma clang fp contract(off)
    const int b = blockIdx.x;
    const int t = threadIdx.x;
    const float* __restrict__ pb = pts + (size_t)b * NP * 3;
    float* __restrict__ out_idx = out + (size_t)b * NS;
    float* __restrict__ out_pts = out + (size_t)NB * NS + (size_t)b * NS * 3;

    __shared__ int sel_hist[NS];
    __shared__ unsigned long long cand[16];
    __shared__ int sel_sh;

    // running min-distance, register-resident (static indexing only)
    float md[PPT];
#pragma unroll
    for (int i = 0; i < PPT; ++i) md[i] = 1e10f;

    if (t == 0) {
        sel_hist[0] = 0;
        out_idx[0] = 0.0f;
    }

    // q = points[0] (first selected index is 0, per reference)
    float qx = pb[0], qy = pb[1], qz = pb[2];

    const int wave = t >> 6;
    const int lane = t & 63;

    for (int s = 1; s < NS; ++s) {
        float bestv = -1.0f;
        int besti = 0;
#pragma unroll
        for (int i = 0; i < PPT; ++i) {
            const int gi = t + i * NT;          // ascending global idx per thread
            const float* __restrict__ p = pb + (size_t)gi * 3;
            float dx = p[0] - qx;
            float dy = p[1] - qy;
            float dz = p[2] - qz;
            float d = (dx * dx + dy * dy) + dz * dz;   // match XLA reduce order
            float nmd = fminf(md[i], d);
            md[i] = nmd;
            if (nmd > bestv) {                  // strict > keeps earliest idx
                bestv = nmd;
                besti = gi;
            }
        }
        // pack (value, ~idx) so u64 max == (max value, min idx)
        unsigned long long pk =
            ((unsigned long long)__float_as_uint(bestv) << 32) |
            (unsigned long long)(0xFFFFFFFFu - (unsigned)besti);
        // wave-level reduce (64 lanes)
#pragma unroll
        for (int m = 32; m >= 1; m >>= 1) {
            unsigned long long o = __shfl_xor(pk, m, 64);
            pk = (o > pk) ? o : pk;
        }
        if (lane == 0) cand[wave] = pk;
        __syncthreads();
        if (wave == 0) {
            unsigned long long c = (lane < 16) ? cand[lane] : 0ull;
#pragma unroll
            for (int m = 8; m >= 1; m >>= 1) {
                unsigned long long o = __shfl_xor(c, m, 64);
                c = (o > c) ? o : c;
            }
            if (lane == 0) {
                int w = (int)(0xFFFFFFFFu - (unsigned)(c & 0xFFFFFFFFull));
                sel_sh = w;
                sel_hist[s] = w;
                out_idx[s] = (float)w;
            }
        }
        __syncthreads();
        const int sel = sel_sh;
        const float* __restrict__ q = pb + (size_t)sel * 3;
        qx = q[0];
        qy = q[1];
        qz = q[2];
        // no extra barrier needed: next cand[] write happens after the
        // barrier above; next sel_sh write happens after the next first
        // barrier, which is after every thread's read of sel_sh here.
    }

    __syncthreads();
    // gather sampled points: one sample per thread
    {
        const int gi = sel_hist[t];
        const float* __restrict__ p = pb + (size_t)gi * 3;
        out_pts[(size_t)t * 3 + 0] = p[0];
        out_pts[(size_t)t * 3 + 1] = p[1];
        out_pts[(size_t)t * 3 + 2] = p[2];
    }
}

extern "C" void kernel_launch(void* const* d_in, const int* in_sizes, int n_in,
                              void* d_out, int out_size, void* d_ws, size_t ws_size,
                              hipStream_t stream) {
    const float* pts = (const float*)d_in[0];
    float* out = (float*)d_out;
    (void)in_sizes; (void)n_in; (void)out_size; (void)d_ws; (void)ws_size;
    hipLaunchKernelGGL(fps_kernel, dim3(NB), dim3(NT), 0, stream, pts, out);
}

// Round 2
// 28501.965 us; speedup vs baseline: 1.0115x; 1.0115x over previous
//
#include <hip/hip_runtime.h>

#define NB 32
#define NP 65536
#define NS 1024
#define NT 1024
#define PPT (NP / NT)   // 64 points per thread

// 4 waves/EU (2nd arg) -> VGPR cap 128: md[64] stays in registers (R1 spilled
// at the default 64-VGPR target: FETCH 95MB/WRITE 33MB of scratch traffic).
__global__ __launch_bounds__(NT, 4) void fps_kernel(const float* __restrict__ pts,
                                                    float* __restrict__ out) {
#pragma clang fp contract(off)
    const int b = blockIdx.x;
    const int t = threadIdx.x;
    const float* __restrict__ pb = pts + (size_t)b * NP * 3;
    float* __restrict__ out_idx = out + (size_t)b * NS;
    float* __restrict__ out_pts = out + (size_t)NB * NS + (size_t)b * NS * 3;

    __shared__ int sel_hist[NS];
    __shared__ unsigned long long cand[16];
    __shared__ int sel_sh;

    // running min-distance, register-resident (static indexing only)
    float md[PPT];
#pragma unroll
    for (int i = 0; i < PPT; ++i) md[i] = 1e10f;

    if (t == 0) {
        sel_hist[0] = 0;
        out_idx[0] = 0.0f;
    }

    // q = points[0] (first selected index is 0, per reference)
    float qx = pb[0], qy = pb[1], qz = pb[2];

    const int wave = t >> 6;
    const int lane = t & 63;

    for (int s = 1; s < NS; ++s) {
        float bestv = -1.0f;
        int besti = 0;
#pragma unroll
        for (int i = 0; i < PPT; ++i) {
            const int gi = t + i * NT;          // ascending global idx per thread
            const float* __restrict__ p = pb + (size_t)gi * 3;
            float dx = p[0] - qx;
            float dy = p[1] - qy;
            float dz = p[2] - qz;
            float d = (dx * dx + dy * dy) + dz * dz;   // match XLA reduce order
            float nmd = fminf(md[i], d);
            md[i] = nmd;
            if (nmd > bestv) {                  // strict > keeps earliest idx
                bestv = nmd;
                besti = gi;
            }
        }
        // pack (value, ~idx) so u64 max == (max value, min idx)
        unsigned long long pk =
            ((unsigned long long)__float_as_uint(bestv) << 32) |
            (unsigned long long)(0xFFFFFFFFu - (unsigned)besti);
        // wave-level reduce (64 lanes)
#pragma unroll
        for (int m = 32; m >= 1; m >>= 1) {
            unsigned long long o = __shfl_xor(pk, m, 64);
            pk = (o > pk) ? o : pk;
        }
        if (lane == 0) cand[wave] = pk;
        __syncthreads();
        if (wave == 0) {
            unsigned long long c = (lane < 16) ? cand[lane] : 0ull;
#pragma unroll
            for (int m = 8; m >= 1; m >>= 1) {
                unsigned long long o = __shfl_xor(c, m, 64);
                c = (o > c) ? o : c;
            }
            if (lane == 0) {
                int w = (int)(0xFFFFFFFFu - (unsigned)(c & 0xFFFFFFFFull));
                sel_sh = w;
                sel_hist[s] = w;
                out_idx[s] = (float)w;
            }
        }
        __syncthreads();
        const int sel = sel_sh;
        const float* __restrict__ q = pb + (size_t)sel * 3;
        qx = q[0];
        qy = q[1];
        qz = q[2];
    }

    __syncthreads();
    // gather sampled points: one sample per thread
    {
        const int gi = sel_hist[t];
        const float* __restrict__ p = pb + (size_t)gi * 3;
        out_pts[(size_t)t * 3 + 0] = p[0];
        out_pts[(size_t)t * 3 + 1] = p[1];
        out_pts[(size_t)t * 3 + 2] = p[2];
    }
}

extern "C" void kernel_launch(void* const* d_in, const int* in_sizes, int n_in,
                              void* d_out, int out_size, void* d_ws, size_t ws_size,
                              hipStream_t stream) {
    const float* pts = (const float*)d_in[0];
    float* out = (float*)d_out;
    (void)in_sizes; (void)n_in; (void)out_size; (void)d_ws; (void)ws_size;
    hipLaunchKernelGGL(fps_kernel, dim3(NB), dim3(NT), 0, stream, pts, out);
}

// Round 3
// 28325.433 us; speedup vs baseline: 1.0178x; 1.0062x over previous
//
#include <hip/hip_runtime.h>

#define NB 32
#define NP 65536
#define NS 1024
#define NT 1024
#define PPT (NP / NT)   // 64 points per thread

// Force exactly 4 waves/EU (16-wave block = 1 block/CU) -> 128-VGPR budget.
// R2 lesson: __launch_bounds__(NT,4) is only a MIN; allocator still chose
// 64 VGPR and spilled md[64] (WRITE_SIZE 33MB of scratch). Pin min=max=4.
__global__ __attribute__((amdgpu_flat_work_group_size(1024, 1024),
                          amdgpu_waves_per_eu(4, 4)))
void fps_kernel(const float* __restrict__ pts, float* __restrict__ out) {
#pragma clang fp contract(off)
    const int b = blockIdx.x;
    const int t = threadIdx.x;
    const float* __restrict__ pb = pts + (size_t)b * NP * 3;
    float* __restrict__ out_idx = out + (size_t)b * NS;
    float* __restrict__ out_pts = out + (size_t)NB * NS + (size_t)b * NS * 3;

    __shared__ int sel_hist[NS];
    __shared__ unsigned long long cand[16];
    __shared__ int sel_sh;

    // running min-distance, register-resident (static indexing only)
    float md[PPT];
#pragma unroll
    for (int i = 0; i < PPT; ++i) md[i] = 1e10f;

    if (t == 0) {
        sel_hist[0] = 0;
        out_idx[0] = 0.0f;
    }

    // q = points[0] (first selected index is 0, per reference)
    float qx = pb[0], qy = pb[1], qz = pb[2];

    const int wave = t >> 6;
    const int lane = t & 63;

    for (int s = 1; s < NS; ++s) {
        float bestv = -1.0f;
        int besti = 0;
        // chunked 8x8: keeps the compiler's load-prefetch window small so
        // register pressure stays under the 128-VGPR budget (no re-spill)
#pragma unroll
        for (int c = 0; c < PPT / 8; ++c) {
#pragma unroll
            for (int u = 0; u < 8; ++u) {
                const int i = c * 8 + u;
                const int gi = t + i * NT;      // ascending global idx
                const float* __restrict__ p = pb + (size_t)gi * 3;
                float dx = p[0] - qx;
                float dy = p[1] - qy;
                float dz = p[2] - qz;
                float d = (dx * dx + dy * dy) + dz * dz;  // match np order
                float nmd = fminf(md[i], d);
                md[i] = nmd;
                if (nmd > bestv) {              // strict > keeps earliest idx
                    bestv = nmd;
                    besti = gi;
                }
            }
        }
        // pack (value, ~idx) so u64 max == (max value, min idx)
        unsigned long long pk =
            ((unsigned long long)__float_as_uint(bestv) << 32) |
            (unsigned long long)(0xFFFFFFFFu - (unsigned)besti);
        // wave-level reduce (64 lanes)
#pragma unroll
        for (int m = 32; m >= 1; m >>= 1) {
            unsigned long long o = __shfl_xor(pk, m, 64);
            pk = (o > pk) ? o : pk;
        }
        if (lane == 0) cand[wave] = pk;
        __syncthreads();
        if (wave == 0) {
            unsigned long long c = (lane < 16) ? cand[lane] : 0ull;
#pragma unroll
            for (int m = 8; m >= 1; m >>= 1) {
                unsigned long long o = __shfl_xor(c, m, 64);
                c = (o > c) ? o : c;
            }
            if (lane == 0) {
                int w = (int)(0xFFFFFFFFu - (unsigned)(c & 0xFFFFFFFFull));
                sel_sh = w;
                sel_hist[s] = w;
                out_idx[s] = (float)w;
            }
        }
        __syncthreads();
        const int sel = sel_sh;
        const float* __restrict__ q = pb + (size_t)sel * 3;
        qx = q[0];
        qy = q[1];
        qz = q[2];
    }

    __syncthreads();
    // gather sampled points: one sample per thread
    {
        const int gi = sel_hist[t];
        const float* __restrict__ p = pb + (size_t)gi * 3;
        out_pts[(size_t)t * 3 + 0] = p[0];
        out_pts[(size_t)t * 3 + 1] = p[1];
        out_pts[(size_t)t * 3 + 2] = p[2];
    }
}

extern "C" void kernel_launch(void* const* d_in, const int* in_sizes, int n_in,
                              void* d_out, int out_size, void* d_ws, size_t ws_size,
                              hipStream_t stream) {
    const float* pts = (const float*)d_in[0];
    float* out = (float*)d_out;
    (void)in_sizes; (void)n_in; (void)out_size; (void)d_ws; (void)ws_size;
    hipLaunchKernelGGL(fps_kernel, dim3(NB), dim3(NT), 0, stream, pts, out);
}

// Round 4
// 8953.136 us; speedup vs baseline: 3.2200x; 3.1637x over previous
//
#include <hip/hip_runtime.h>

#define NB 32
#define NP 65536
#define NS 1024
#define NT 1024

typedef unsigned long long u64;
typedef unsigned int u32;

// ---------------- multi-block kernel: 8 blocks per batch ----------------
#define BPB 8                 // blocks per batch
#define CHUNK (NP / BPB)      // 8192 points per block
#define PPT2 (CHUNK / NT)     // 8 points per thread -> md[8] fits 64 VGPRs

__global__ __launch_bounds__(NT) void fps_multi(const float* __restrict__ pts,
                                                float* __restrict__ out,
                                                u64* __restrict__ winner,
                                                u32* __restrict__ count) {
#pragma clang fp contract(off)
    const int bid = blockIdx.x;
    const int b = bid >> 3;           // batch
    const int j = bid & 7;            // sub-block within batch
    const int t = threadIdx.x;
    const int base = j * CHUNK;
    const float* __restrict__ pb = pts + (size_t)b * NP * 3;
    float* __restrict__ out_idx = out + (size_t)b * NS;
    float* __restrict__ out_pts = out + (size_t)NB * NS + (size_t)b * NS * 3;
    u64* __restrict__ win_b = winner + (size_t)b * NS;
    u32* __restrict__ cnt_b = count + (size_t)b * NS;

    __shared__ float P[CHUNK * 3];    // 96 KB: this block's point chunk (xyz interleaved)
    __shared__ u64 cand[NT / 64];
    __shared__ int sel_hist[NS];      // consumed by j==0 for the final gather
    __shared__ float qsh[3];

    // stage chunk into LDS, coalesced float4 (LDS bits identical to global)
    {
        const float4* __restrict__ src4 = (const float4*)(pb + (size_t)base * 3);
        float4* dst4 = (float4*)P;
#pragma unroll
        for (int k = 0; k < (CHUNK * 3 / 4) / NT; ++k) dst4[t + k * NT] = src4[t + k * NT];
    }

    float md[PPT2];
#pragma unroll
    for (int i = 0; i < PPT2; ++i) md[i] = 1e10f;

    if (t == 0) {
        sel_hist[0] = 0;
        if (j == 0) out_idx[0] = 0.0f;
        qsh[0] = pb[0]; qsh[1] = pb[1]; qsh[2] = pb[2];   // first sel = point 0
    }
    __syncthreads();

    float qx = qsh[0], qy = qsh[1], qz = qsh[2];

    const int wave = t >> 6;
    const int lane = t & 63;

    for (int s = 1; s < NS; ++s) {
        float bestv = -1.0f;
        int besti = 0;
#pragma unroll
        for (int i = 0; i < PPT2; ++i) {
            const int li = t + i * NT;                 // ascending local idx
            const float* __restrict__ p = P + li * 3;  // lanes hit distinct banks (3 coprime 32)
            float dx = p[0] - qx;
            float dy = p[1] - qy;
            float dz = p[2] - qz;
            float d = (dx * dx + dy * dy) + dz * dz;   // match np reduce order (verified R1)
            float nmd = fminf(md[i], d);
            md[i] = nmd;
            if (nmd > bestv) { bestv = nmd; besti = li; }  // strict > keeps earliest idx
        }
        // pack (value, ~global_idx): u64 max == (max value, then min idx); always > 0
        u64 pk = ((u64)__float_as_uint(bestv) << 32) |
                 (u64)(0xFFFFFFFFu - (u32)(base + besti));
#pragma unroll
        for (int m = 32; m >= 1; m >>= 1) {
            u64 o = __shfl_xor(pk, m, 64);
            pk = (o > pk) ? o : pk;
        }
        if (lane == 0) cand[wave] = pk;
        __syncthreads();
        if (t == 0) {
            u64 c = cand[0];
#pragma unroll
            for (int w = 1; w < NT / 64; ++w) c = (cand[w] > c) ? cand[w] : c;
            atomicMax(win_b + s, c);                   // device-scope by default
            __threadfence();                           // winner visible before count
            atomicAdd(cnt_b + s, 1u);
            while (__hip_atomic_load(cnt_b + s, __ATOMIC_ACQUIRE,
                                     __HIP_MEMORY_SCOPE_AGENT) < BPB) {
                __builtin_amdgcn_s_sleep(2);
            }
            u64 wv = __hip_atomic_load(win_b + s, __ATOMIC_ACQUIRE,
                                       __HIP_MEMORY_SCOPE_AGENT);
            int w = (int)(0xFFFFFFFFu - (u32)(wv & 0xFFFFFFFFull));
            sel_hist[s] = w;
            const float* __restrict__ q = pb + (size_t)w * 3;
            qsh[0] = q[0]; qsh[1] = q[1]; qsh[2] = q[2];
            if (j == 0) out_idx[s] = (float)w;
        }
        __syncthreads();
        qx = qsh[0]; qy = qsh[1]; qz = qsh[2];
    }

    if (j == 0) {
        const int gi = sel_hist[t];
        const float* __restrict__ p = pb + (size_t)gi * 3;
        out_pts[(size_t)t * 3 + 0] = p[0];
        out_pts[(size_t)t * 3 + 1] = p[1];
        out_pts[(size_t)t * 3 + 2] = p[2];
    }
}

// ---------------- fallback: verified single-block-per-batch kernel ----------------
#define PPT (NP / NT)
__global__ __launch_bounds__(NT) void fps_kernel(const float* __restrict__ pts,
                                                 float* __restrict__ out) {
#pragma clang fp contract(off)
    const int b = blockIdx.x;
    const int t = threadIdx.x;
    const float* __restrict__ pb = pts + (size_t)b * NP * 3;
    float* __restrict__ out_idx = out + (size_t)b * NS;
    float* __restrict__ out_pts = out + (size_t)NB * NS + (size_t)b * NS * 3;
    __shared__ int sel_hist[NS];
    __shared__ u64 cand[16];
    __shared__ int sel_sh;
    float md[PPT];
#pragma unroll
    for (int i = 0; i < PPT; ++i) md[i] = 1e10f;
    if (t == 0) { sel_hist[0] = 0; out_idx[0] = 0.0f; }
    float qx = pb[0], qy = pb[1], qz = pb[2];
    const int wave = t >> 6;
    const int lane = t & 63;
    for (int s = 1; s < NS; ++s) {
        float bestv = -1.0f;
        int besti = 0;
#pragma unroll
        for (int i = 0; i < PPT; ++i) {
            const int gi = t + i * NT;
            const float* __restrict__ p = pb + (size_t)gi * 3;
            float dx = p[0] - qx, dy = p[1] - qy, dz = p[2] - qz;
            float d = (dx * dx + dy * dy) + dz * dz;
            float nmd = fminf(md[i], d);
            md[i] = nmd;
            if (nmd > bestv) { bestv = nmd; besti = gi; }
        }
        u64 pk = ((u64)__float_as_uint(bestv) << 32) |
                 (u64)(0xFFFFFFFFu - (u32)besti);
#pragma unroll
        for (int m = 32; m >= 1; m >>= 1) {
            u64 o = __shfl_xor(pk, m, 64);
            pk = (o > pk) ? o : pk;
        }
        if (lane == 0) cand[wave] = pk;
        __syncthreads();
        if (wave == 0) {
            u64 c = (lane < 16) ? cand[lane] : 0ull;
#pragma unroll
            for (int m = 8; m >= 1; m >>= 1) {
                u64 o = __shfl_xor(c, m, 64);
                c = (o > c) ? o : c;
            }
            if (lane == 0) {
                int w = (int)(0xFFFFFFFFu - (u32)(c & 0xFFFFFFFFull));
                sel_sh = w; sel_hist[s] = w; out_idx[s] = (float)w;
            }
        }
        __syncthreads();
        const int sel = sel_sh;
        qx = pb[(size_t)sel * 3]; qy = pb[(size_t)sel * 3 + 1]; qz = pb[(size_t)sel * 3 + 2];
    }
    __syncthreads();
    {
        const int gi = sel_hist[t];
        const float* __restrict__ p = pb + (size_t)gi * 3;
        out_pts[(size_t)t * 3 + 0] = p[0];
        out_pts[(size_t)t * 3 + 1] = p[1];
        out_pts[(size_t)t * 3 + 2] = p[2];
    }
}

extern "C" void kernel_launch(void* const* d_in, const int* in_sizes, int n_in,
                              void* d_out, int out_size, void* d_ws, size_t ws_size,
                              hipStream_t stream) {
    const float* pts = (const float*)d_in[0];
    float* out = (float*)d_out;
    (void)in_sizes; (void)n_in; (void)out_size;

    const size_t win_bytes = (size_t)NB * NS * sizeof(u64);   // 256 KB
    const size_t cnt_bytes = (size_t)NB * NS * sizeof(u32);   // 128 KB
    if (ws_size >= win_bytes + cnt_bytes) {
        u64* winner = (u64*)d_ws;
        u32* count = (u32*)((char*)d_ws + win_bytes);
        hipMemsetAsync(d_ws, 0, win_bytes + cnt_bytes, stream);
        void* args[] = {(void*)&pts, (void*)&out, (void*)&winner, (void*)&count};
        hipLaunchCooperativeKernel((const void*)fps_multi, dim3(NB * BPB), dim3(NT),
                                   args, 0, stream);
    } else {
        hipLaunchKernelGGL(fps_kernel, dim3(NB), dim3(NT), 0, stream, pts, out);
    }
}

// Round 5
// 2616.120 us; speedup vs baseline: 11.0197x; 3.4223x over previous
//
#include <hip/hip_runtime.h>

#define NB 32
#define NP 65536
#define NS 1024
#define NT 1024

typedef unsigned long long u64;
typedef unsigned int u32;

#define BPB 8                 // blocks per batch
#define CHUNK (NP / BPB)      // 8192 points per block
#define PPT2 (CHUNK / NT)     // 8 points per thread

// ---------------- R5: contention-free slot-store protocol ----------------
// Each (batch,s) has 8 u64 slots in one 64B line. Writers STORE (no RMW, no
// wait); 8 lanes of wave0 poll the line (one coalesced load per round trip),
// shuffle-max, broadcast. Packed key (value<<32)|~idx is always nonzero.
__global__ __launch_bounds__(NT) void fps_slots(const float* __restrict__ pts,
                                                float* __restrict__ out,
                                                u64* __restrict__ slots) {
#pragma clang fp contract(off)
    const int bid = blockIdx.x;
    const int b = bid >> 3;           // batch
    const int j = bid & 7;            // sub-block within batch
    const int t = threadIdx.x;
    const int base = j * CHUNK;
    const float* __restrict__ pb = pts + (size_t)b * NP * 3;
    float* __restrict__ out_idx = out + (size_t)b * NS;
    float* __restrict__ out_pts = out + (size_t)NB * NS + (size_t)b * NS * 3;
    u64* __restrict__ slot_b = slots + (size_t)b * NS * BPB;

    __shared__ float P[CHUNK * 3];    // 96 KB point chunk
    __shared__ u64 cand[NT / 64];
    __shared__ int sel_hist[NS];
    __shared__ float qsh[3];

    // stage chunk into LDS, coalesced float4
    {
        const float4* __restrict__ src4 = (const float4*)(pb + (size_t)base * 3);
        float4* dst4 = (float4*)P;
#pragma unroll
        for (int k = 0; k < (CHUNK * 3 / 4) / NT; ++k) dst4[t + k * NT] = src4[t + k * NT];
    }

    float md[PPT2];
#pragma unroll
    for (int i = 0; i < PPT2; ++i) md[i] = 1e10f;

    if (t == 0) {
        sel_hist[0] = 0;
        if (j == 0) out_idx[0] = 0.0f;
        qsh[0] = pb[0]; qsh[1] = pb[1]; qsh[2] = pb[2];   // first sel = point 0
    }
    __syncthreads();

    float qx = qsh[0], qy = qsh[1], qz = qsh[2];

    const int wave = t >> 6;
    const int lane = t & 63;

    for (int s = 1; s < NS; ++s) {
        float bestv = -1.0f;
        int besti = 0;
#pragma unroll
        for (int i = 0; i < PPT2; ++i) {
            const int li = t + i * NT;
            const float* __restrict__ p = P + li * 3;
            float dx = p[0] - qx;
            float dy = p[1] - qy;
            float dz = p[2] - qz;
            float d = (dx * dx + dy * dy) + dz * dz;   // match np reduce order
            float nmd = fminf(md[i], d);
            md[i] = nmd;
            if (nmd > bestv) { bestv = nmd; besti = li; }  // strict >: earliest idx
        }
        u64 pk = ((u64)__float_as_uint(bestv) << 32) |
                 (u64)(0xFFFFFFFFu - (u32)(base + besti));
#pragma unroll
        for (int m = 32; m >= 1; m >>= 1) {
            u64 o = __shfl_xor(pk, m, 64);
            pk = (o > pk) ? o : pk;
        }
        if (lane == 0) cand[wave] = pk;
        __syncthreads();
        if (wave == 0) {
            // block reduce over the 16 wave candidates (lanes 0..15)
            u64 c = (lane < 16) ? cand[lane] : 0ull;
#pragma unroll
            for (int m = 8; m >= 1; m >>= 1) {
                u64 o = __shfl_xor(c, m, 64);
                c = (o > c) ? o : c;
            }
            if (lane == 0) {
                __hip_atomic_store(&slot_b[(size_t)s * BPB + j], c,
                                   __ATOMIC_RELAXED, __HIP_MEMORY_SCOPE_AGENT);
            }
            // poll: lane k < 8 watches slot k; one coalesced line-load per round
            u64 x = 0;
            if (lane < BPB) {
                const u64* sp = &slot_b[(size_t)s * BPB + lane];
                while ((x = __hip_atomic_load(sp, __ATOMIC_RELAXED,
                                              __HIP_MEMORY_SCOPE_AGENT)) == 0ull) {
                    __builtin_amdgcn_s_sleep(1);
                }
            }
#pragma unroll
            for (int m = 4; m >= 1; m >>= 1) {
                u64 o = __shfl_xor(x, m, 64);
                x = (o > x) ? o : x;
            }
            if (lane == 0) {
                int w = (int)(0xFFFFFFFFu - (u32)(x & 0xFFFFFFFFull));
                sel_hist[s] = w;
                const float* __restrict__ q = pb + (size_t)w * 3;
                qsh[0] = q[0]; qsh[1] = q[1]; qsh[2] = q[2];
                if (j == 0) out_idx[s] = (float)w;
            }
        }
        __syncthreads();
        qx = qsh[0]; qy = qsh[1]; qz = qsh[2];
    }

    if (j == 0) {
        const int gi = sel_hist[t];
        const float* __restrict__ p = pb + (size_t)gi * 3;
        out_pts[(size_t)t * 3 + 0] = p[0];
        out_pts[(size_t)t * 3 + 1] = p[1];
        out_pts[(size_t)t * 3 + 2] = p[2];
    }
}

// ---------------- R4 fallback: atomicMax + counter protocol ----------------
__global__ __launch_bounds__(NT) void fps_multi(const float* __restrict__ pts,
                                                float* __restrict__ out,
                                                u64* __restrict__ winner,
                                                u32* __restrict__ count) {
#pragma clang fp contract(off)
    const int bid = blockIdx.x;
    const int b = bid >> 3;
    const int j = bid & 7;
    const int t = threadIdx.x;
    const int base = j * CHUNK;
    const float* __restrict__ pb = pts + (size_t)b * NP * 3;
    float* __restrict__ out_idx = out + (size_t)b * NS;
    float* __restrict__ out_pts = out + (size_t)NB * NS + (size_t)b * NS * 3;
    u64* __restrict__ win_b = winner + (size_t)b * NS;
    u32* __restrict__ cnt_b = count + (size_t)b * NS;

    __shared__ float P[CHUNK * 3];
    __shared__ u64 cand[NT / 64];
    __shared__ int sel_hist[NS];
    __shared__ float qsh[3];

    {
        const float4* __restrict__ src4 = (const float4*)(pb + (size_t)base * 3);
        float4* dst4 = (float4*)P;
#pragma unroll
        for (int k = 0; k < (CHUNK * 3 / 4) / NT; ++k) dst4[t + k * NT] = src4[t + k * NT];
    }
    float md[PPT2];
#pragma unroll
    for (int i = 0; i < PPT2; ++i) md[i] = 1e10f;
    if (t == 0) {
        sel_hist[0] = 0;
        if (j == 0) out_idx[0] = 0.0f;
        qsh[0] = pb[0]; qsh[1] = pb[1]; qsh[2] = pb[2];
    }
    __syncthreads();
    float qx = qsh[0], qy = qsh[1], qz = qsh[2];
    const int wave = t >> 6;
    const int lane = t & 63;
    for (int s = 1; s < NS; ++s) {
        float bestv = -1.0f;
        int besti = 0;
#pragma unroll
        for (int i = 0; i < PPT2; ++i) {
            const int li = t + i * NT;
            const float* __restrict__ p = P + li * 3;
            float dx = p[0] - qx, dy = p[1] - qy, dz = p[2] - qz;
            float d = (dx * dx + dy * dy) + dz * dz;
            float nmd = fminf(md[i], d);
            md[i] = nmd;
            if (nmd > bestv) { bestv = nmd; besti = li; }
        }
        u64 pk = ((u64)__float_as_uint(bestv) << 32) |
                 (u64)(0xFFFFFFFFu - (u32)(base + besti));
#pragma unroll
        for (int m = 32; m >= 1; m >>= 1) {
            u64 o = __shfl_xor(pk, m, 64);
            pk = (o > pk) ? o : pk;
        }
        if (lane == 0) cand[wave] = pk;
        __syncthreads();
        if (t == 0) {
            u64 c = cand[0];
#pragma unroll
            for (int w = 1; w < NT / 64; ++w) c = (cand[w] > c) ? cand[w] : c;
            atomicMax(win_b + s, c);
            __threadfence();
            atomicAdd(cnt_b + s, 1u);
            while (__hip_atomic_load(cnt_b + s, __ATOMIC_ACQUIRE,
                                     __HIP_MEMORY_SCOPE_AGENT) < BPB) {
                __builtin_amdgcn_s_sleep(2);
            }
            u64 wv = __hip_atomic_load(win_b + s, __ATOMIC_ACQUIRE,
                                       __HIP_MEMORY_SCOPE_AGENT);
            int w = (int)(0xFFFFFFFFu - (u32)(wv & 0xFFFFFFFFull));
            sel_hist[s] = w;
            const float* __restrict__ q = pb + (size_t)w * 3;
            qsh[0] = q[0]; qsh[1] = q[1]; qsh[2] = q[2];
            if (j == 0) out_idx[s] = (float)w;
        }
        __syncthreads();
        qx = qsh[0]; qy = qsh[1]; qz = qsh[2];
    }
    if (j == 0) {
        const int gi = sel_hist[t];
        const float* __restrict__ p = pb + (size_t)gi * 3;
        out_pts[(size_t)t * 3 + 0] = p[0];
        out_pts[(size_t)t * 3 + 1] = p[1];
        out_pts[(size_t)t * 3 + 2] = p[2];
    }
}

extern "C" void kernel_launch(void* const* d_in, const int* in_sizes, int n_in,
                              void* d_out, int out_size, void* d_ws, size_t ws_size,
                              hipStream_t stream) {
    const float* pts = (const float*)d_in[0];
    float* out = (float*)d_out;
    (void)in_sizes; (void)n_in; (void)out_size;

    const size_t slot_bytes = (size_t)NB * NS * BPB * sizeof(u64);  // 2 MB
    const size_t win_bytes = (size_t)NB * NS * sizeof(u64);         // 256 KB
    const size_t cnt_bytes = (size_t)NB * NS * sizeof(u32);         // 128 KB
    if (ws_size >= slot_bytes) {
        u64* slots = (u64*)d_ws;
        hipMemsetAsync(d_ws, 0, slot_bytes, stream);
        void* args[] = {(void*)&pts, (void*)&out, (void*)&slots};
        hipLaunchCooperativeKernel((const void*)fps_slots, dim3(NB * BPB), dim3(NT),
                                   args, 0, stream);
    } else {
        u64* winner = (u64*)d_ws;
        u32* count = (u32*)((char*)d_ws + win_bytes);
        hipMemsetAsync(d_ws, 0, win_bytes + cnt_bytes, stream);
        void* args[] = {(void*)&pts, (void*)&out, (void*)&winner, (void*)&count};
        hipLaunchCooperativeKernel((const void*)fps_multi, dim3(NB * BPB), dim3(NT),
                                   args, 0, stream);
    }
}

// Round 6
// 2557.800 us; speedup vs baseline: 11.2709x; 1.0228x over previous
//
#include <hip/hip_runtime.h>

#define NB 32
#define NP 65536
#define NS 1024
#define NT 1024
#define BPB 8                 // blocks per batch
#define CHUNK (NP / BPB)      // 8192 points per block
#define PPT2 (CHUNK / NT)     // 8 points per thread

typedef unsigned long long u64;
typedef unsigned int u32;
typedef int int4v __attribute__((ext_vector_type(4)));

// ---------------- R6: coords-in-slot protocol ----------------
// Slot = 32B, two 16B halves: h0={k_lo,k_hi,x,y} h1={k_lo,k_hi,z,0}.
// Writer: two dwordx4 stores (sc0 sc1 -> LLC, agent-visible). Poller: two
// dwordx4 loads in one asm; valid iff k!=0 && h0.key==h1.key. Winner coords
// ride the poll line -> removes the serial post-detect q-fetch of R5.
__global__ __launch_bounds__(NT) void fps_v6(const float* __restrict__ pts,
                                             float* __restrict__ out,
                                             u32* __restrict__ slots) {
#pragma clang fp contract(off)
    const int bid = blockIdx.x;
    const int b = bid >> 3;           // batch
    const int j = bid & 7;            // sub-block within batch
    const int t = threadIdx.x;
    const int base = j * CHUNK;
    const float* __restrict__ pb = pts + (size_t)b * NP * 3;
    float* __restrict__ out_idx = out + (size_t)b * NS;
    float* __restrict__ out_pts = out + (size_t)NB * NS + (size_t)b * NS * 3;
    u32* __restrict__ slot_b = slots + (size_t)b * NS * BPB * 8;  // u32 words

    __shared__ float4 P4[CHUNK];      // 128 KB padded points (b128-friendly)
    __shared__ u64 cand[NT / 64];
    __shared__ int sel_hist[NS];
    __shared__ float qsh[3];

    // stage chunk: 12B-packed -> 16B-padded, 4 points per 3 float4 reads
    {
        const float4* __restrict__ src4 = (const float4*)(pb + (size_t)base * 3);
#pragma unroll
        for (int k2 = 0; k2 < CHUNK / 4 / NT; ++k2) {
            const int g = t + k2 * NT;            // point-group (4 pts)
            float4 A = src4[g * 3 + 0];
            float4 B = src4[g * 3 + 1];
            float4 C = src4[g * 3 + 2];
            P4[g * 4 + 0] = make_float4(A.x, A.y, A.z, 0.f);
            P4[g * 4 + 1] = make_float4(A.w, B.x, B.y, 0.f);
            P4[g * 4 + 2] = make_float4(B.z, B.w, C.x, 0.f);
            P4[g * 4 + 3] = make_float4(C.y, C.z, C.w, 0.f);
        }
    }

    float md[PPT2];
#pragma unroll
    for (int i = 0; i < PPT2; ++i) md[i] = 1e10f;

    if (t == 0) {
        sel_hist[0] = 0;
        if (j == 0) out_idx[0] = 0.0f;
        qsh[0] = pb[0]; qsh[1] = pb[1]; qsh[2] = pb[2];   // first sel = point 0
    }
    __syncthreads();

    float qx = qsh[0], qy = qsh[1], qz = qsh[2];

    const int wave = t >> 6;
    const int lane = t & 63;

    for (int s = 1; s < NS; ++s) {
        float bestv = -1.0f;
        int besti = 0;
#pragma unroll
        for (int i = 0; i < PPT2; ++i) {
            const int li = t + i * NT;
            float4 p = P4[li];                         // ds_read_b128, no conflict
            float dx = p.x - qx;
            float dy = p.y - qy;
            float dz = p.z - qz;
            float d = (dx * dx + dy * dy) + dz * dz;   // match np reduce order
            float nmd = fminf(md[i], d);
            md[i] = nmd;
            if (nmd > bestv) { bestv = nmd; besti = li; }  // strict >: earliest idx
        }
        u64 pk = ((u64)__float_as_uint(bestv) << 32) |
                 (u64)(0xFFFFFFFFu - (u32)(base + besti));
#pragma unroll
        for (int m = 32; m >= 1; m >>= 1) {
            u64 o = __shfl_xor(pk, m, 64);
            pk = (o > pk) ? o : pk;
        }
        if (lane == 0) cand[wave] = pk;
        __syncthreads();
        if (wave == 0) {
            // stage-2 block reduce (16 wave candidates)
            u64 c = (lane < 16) ? cand[lane] : 0ull;
#pragma unroll
            for (int m = 8; m >= 1; m >>= 1) {
                u64 o = __shfl_xor(c, m, 64);
                c = (o > c) ? o : c;
            }
            if (lane == 0) {
                // fetch block-winner coords from LDS (local by construction)
                const int gwin = (int)(0xFFFFFFFFu - (u32)(c & 0xFFFFFFFFull));
                const int lwin = gwin - base;
                float4 pw = P4[lwin];
                int4v h0, h1;
                h0.x = (int)(u32)(c & 0xFFFFFFFFull);
                h0.y = (int)(u32)(c >> 32);
                h0.z = __float_as_int(pw.x);
                h0.w = __float_as_int(pw.y);
                h1.x = h0.x;
                h1.y = h0.y;
                h1.z = __float_as_int(pw.z);
                h1.w = 0;
                u32* sp = slot_b + ((size_t)s * BPB + j) * 8;
                asm volatile(
                    "global_store_dwordx4 %0, %2, off sc0 sc1\n\t"
                    "global_store_dwordx4 %1, %3, off sc0 sc1"
                    :: "v"(sp), "v"(sp + 4), "v"(h0), "v"(h1) : "memory");
            }
            // poll: lane k<8 watches slot k; coords ride the same line
            u64 k = 0;
            float wx = 0.f, wy = 0.f, wz = 0.f;
            if (lane < BPB) {
                const u32* pp = slot_b + ((size_t)s * BPB + lane) * 8;
                int4v a, bb;
                for (;;) {
                    asm volatile(
                        "global_load_dwordx4 %0, %2, off sc0 sc1\n\t"
                        "global_load_dwordx4 %1, %3, off sc0 sc1\n\t"
                        "s_waitcnt vmcnt(0)"
                        : "=&v"(a), "=&v"(bb)
                        : "v"(pp), "v"(pp + 4) : "memory");
                    if (a.x != 0 && a.x == bb.x && a.y == bb.y) break;
                    __builtin_amdgcn_s_sleep(1);
                }
                k = ((u64)(u32)a.y << 32) | (u32)a.x;
                wx = __int_as_float(a.z);
                wy = __int_as_float(a.w);
                wz = __int_as_float(bb.z);
            }
#pragma unroll
            for (int m = 4; m >= 1; m >>= 1) {
                u64 o = __shfl_xor(k, m, 64);
                k = (o > k) ? o : k;
            }
            const int g = (int)(0xFFFFFFFFu - (u32)(k & 0xFFFFFFFFull));
            const int jw = (g >> 13) & 7;        // winning block = slot owner
            float sx = __shfl(wx, jw, 64);
            float sy = __shfl(wy, jw, 64);
            float sz = __shfl(wz, jw, 64);
            if (lane == 0) {
                sel_hist[s] = g;
                qsh[0] = sx; qsh[1] = sy; qsh[2] = sz;
                if (j == 0) out_idx[s] = (float)g;
            }
        }
        __syncthreads();
        qx = qsh[0]; qy = qsh[1]; qz = qsh[2];
    }

    if (j == 0) {
        const int gi = sel_hist[t];
        const float* __restrict__ p = pb + (size_t)gi * 3;
        out_pts[(size_t)t * 3 + 0] = p[0];
        out_pts[(size_t)t * 3 + 1] = p[1];
        out_pts[(size_t)t * 3 + 2] = p[2];
    }
}

// ---------------- R5 fallback: verified slot-store protocol (2 MB ws) -------
__global__ __launch_bounds__(NT) void fps_slots(const float* __restrict__ pts,
                                                float* __restrict__ out,
                                                u64* __restrict__ slots) {
#pragma clang fp contract(off)
    const int bid = blockIdx.x;
    const int b = bid >> 3;
    const int j = bid & 7;
    const int t = threadIdx.x;
    const int base = j * CHUNK;
    const float* __restrict__ pb = pts + (size_t)b * NP * 3;
    float* __restrict__ out_idx = out + (size_t)b * NS;
    float* __restrict__ out_pts = out + (size_t)NB * NS + (size_t)b * NS * 3;
    u64* __restrict__ slot_b = slots + (size_t)b * NS * BPB;

    __shared__ float P[CHUNK * 3];
    __shared__ u64 cand[NT / 64];
    __shared__ int sel_hist[NS];
    __shared__ float qsh[3];

    {
        const float4* __restrict__ src4 = (const float4*)(pb + (size_t)base * 3);
        float4* dst4 = (float4*)P;
#pragma unroll
        for (int k = 0; k < (CHUNK * 3 / 4) / NT; ++k) dst4[t + k * NT] = src4[t + k * NT];
    }
    float md[PPT2];
#pragma unroll
    for (int i = 0; i < PPT2; ++i) md[i] = 1e10f;
    if (t == 0) {
        sel_hist[0] = 0;
        if (j == 0) out_idx[0] = 0.0f;
        qsh[0] = pb[0]; qsh[1] = pb[1]; qsh[2] = pb[2];
    }
    __syncthreads();
    float qx = qsh[0], qy = qsh[1], qz = qsh[2];
    const int wave = t >> 6;
    const int lane = t & 63;
    for (int s = 1; s < NS; ++s) {
        float bestv = -1.0f;
        int besti = 0;
#pragma unroll
        for (int i = 0; i < PPT2; ++i) {
            const int li = t + i * NT;
            const float* __restrict__ p = P + li * 3;
            float dx = p[0] - qx, dy = p[1] - qy, dz = p[2] - qz;
            float d = (dx * dx + dy * dy) + dz * dz;
            float nmd = fminf(md[i], d);
            md[i] = nmd;
            if (nmd > bestv) { bestv = nmd; besti = li; }
        }
        u64 pk = ((u64)__float_as_uint(bestv) << 32) |
                 (u64)(0xFFFFFFFFu - (u32)(base + besti));
#pragma unroll
        for (int m = 32; m >= 1; m >>= 1) {
            u64 o = __shfl_xor(pk, m, 64);
            pk = (o > pk) ? o : pk;
        }
        if (lane == 0) cand[wave] = pk;
        __syncthreads();
        if (wave == 0) {
            u64 c = (lane < 16) ? cand[lane] : 0ull;
#pragma unroll
            for (int m = 8; m >= 1; m >>= 1) {
                u64 o = __shfl_xor(c, m, 64);
                c = (o > c) ? o : c;
            }
            if (lane == 0) {
                __hip_atomic_store(&slot_b[(size_t)s * BPB + j], c,
                                   __ATOMIC_RELAXED, __HIP_MEMORY_SCOPE_AGENT);
            }
            u64 x = 0;
            if (lane < BPB) {
                const u64* sp = &slot_b[(size_t)s * BPB + lane];
                while ((x = __hip_atomic_load(sp, __ATOMIC_RELAXED,
                                              __HIP_MEMORY_SCOPE_AGENT)) == 0ull) {
                    __builtin_amdgcn_s_sleep(1);
                }
            }
#pragma unroll
            for (int m = 4; m >= 1; m >>= 1) {
                u64 o = __shfl_xor(x, m, 64);
                x = (o > x) ? o : x;
            }
            if (lane == 0) {
                int w = (int)(0xFFFFFFFFu - (u32)(x & 0xFFFFFFFFull));
                sel_hist[s] = w;
                const float* __restrict__ q = pb + (size_t)w * 3;
                qsh[0] = q[0]; qsh[1] = q[1]; qsh[2] = q[2];
                if (j == 0) out_idx[s] = (float)w;
            }
        }
        __syncthreads();
        qx = qsh[0]; qy = qsh[1]; qz = qsh[2];
    }
    if (j == 0) {
        const int gi = sel_hist[t];
        const float* __restrict__ p = pb + (size_t)gi * 3;
        out_pts[(size_t)t * 3 + 0] = p[0];
        out_pts[(size_t)t * 3 + 1] = p[1];
        out_pts[(size_t)t * 3 + 2] = p[2];
    }
}

extern "C" void kernel_launch(void* const* d_in, const int* in_sizes, int n_in,
                              void* d_out, int out_size, void* d_ws, size_t ws_size,
                              hipStream_t stream) {
    const float* pts = (const float*)d_in[0];
    float* out = (float*)d_out;
    (void)in_sizes; (void)n_in; (void)out_size;

    const size_t v6_bytes = (size_t)NB * NS * BPB * 32;             // 8 MB
    const size_t slot_bytes = (size_t)NB * NS * BPB * sizeof(u64);  // 2 MB
    if (ws_size >= v6_bytes) {
        u32* slots = (u32*)d_ws;
        hipMemsetAsync(d_ws, 0, v6_bytes, stream);
        void* args[] = {(void*)&pts, (void*)&out, (void*)&slots};
        hipLaunchCooperativeKernel((const void*)fps_v6, dim3(NB * BPB), dim3(NT),
                                   args, 0, stream);
    } else {
        u64* slots = (u64*)d_ws;
        hipMemsetAsync(d_ws, 0, slot_bytes, stream);
        void* args[] = {(void*)&pts, (void*)&out, (void*)&slots};
        hipLaunchCooperativeKernel((const void*)fps_slots, dim3(NB * BPB), dim3(NT),
                                   args, 0, stream);
    }
}

// Round 7
// 2222.082 us; speedup vs baseline: 12.9738x; 1.1511x over previous
//
#include <hip/hip_runtime.h>

#define NB 32
#define NP 65536
#define NS 1024
#define NT 1024
#define BPB 8                 // blocks per batch
#define CHUNK (NP / BPB)      // 8192 points per block
#define PPT2 (CHUNK / NT)     // 8 points per thread

typedef unsigned long long u64;
typedef unsigned int u32;
typedef int int4v __attribute__((ext_vector_type(4)));

// ---------------- R7: reg-resident points + own-slot-skip poll --------------
// Slot = 32B, two 16B halves: h0={k_lo,k_hi,x,y} h1={k_lo,k_hi,z,0}; valid iff
// k!=0 && h0.key==h1.key (guards tearing). Writers store (no RMW); lanes 0-7
// poll the 7 FOREIGN slots only (own candidate is in-register) -> no block
// ever stalls on its own store's IF$ round trip (straggler cascade broken).
__global__ __launch_bounds__(NT) void fps_v7(const float* __restrict__ pts,
                                             float* __restrict__ out,
                                             u32* __restrict__ slots) {
#pragma clang fp contract(off)
    const int bid = blockIdx.x;
    const int b = bid >> 3;           // batch
    const int j = bid & 7;            // sub-block within batch
    const int t = threadIdx.x;
    const int base = j * CHUNK;
    const float* __restrict__ pb = pts + (size_t)b * NP * 3;
    float* __restrict__ out_idx = out + (size_t)b * NS;
    float* __restrict__ out_pts = out + (size_t)NB * NS + (size_t)b * NS * 3;
    u32* __restrict__ slot_b = slots + (size_t)b * NS * BPB * 8;  // u32 words

    __shared__ float P[CHUNK * 3];    // 96 KB packed; winner-lookup + gather only
    __shared__ u64 cand[NT / 64];
    __shared__ int sel_hist[NS];
    __shared__ float qsh[3];

    // stage chunk into LDS, coalesced float4
    {
        const float4* __restrict__ src4 = (const float4*)(pb + (size_t)base * 3);
        float4* dst4 = (float4*)P;
#pragma unroll
        for (int k = 0; k < (CHUNK * 3 / 4) / NT; ++k) dst4[t + k * NT] = src4[t + k * NT];
    }

    if (t == 0) {
        sel_hist[0] = 0;
        if (j == 0) out_idx[0] = 0.0f;
        qsh[0] = pb[0]; qsh[1] = pb[1]; qsh[2] = pb[2];   // first sel = point 0
    }
    __syncthreads();

    // points live in registers for the whole kernel (they never change)
    float px[PPT2], py[PPT2], pz[PPT2], md[PPT2];
#pragma unroll
    for (int i = 0; i < PPT2; ++i) {
        const int li = t + i * NT;
        px[i] = P[li * 3 + 0];
        py[i] = P[li * 3 + 1];
        pz[i] = P[li * 3 + 2];
        md[i] = 1e10f;
    }

    float qx = qsh[0], qy = qsh[1], qz = qsh[2];

    const int wave = t >> 6;
    const int lane = t & 63;

    for (int s = 1; s < NS; ++s) {
        float bestv = -1.0f;
        int besti = 0;
#pragma unroll
        for (int i = 0; i < PPT2; ++i) {
            float dx = px[i] - qx;
            float dy = py[i] - qy;
            float dz = pz[i] - qz;
            float d = (dx * dx + dy * dy) + dz * dz;   // match np reduce order
            float nmd = fminf(md[i], d);
            md[i] = nmd;
            if (nmd > bestv) { bestv = nmd; besti = t + i * NT; }  // strict >
        }
        u64 pk = ((u64)__float_as_uint(bestv) << 32) |
                 (u64)(0xFFFFFFFFu - (u32)(base + besti));
#pragma unroll
        for (int m = 32; m >= 1; m >>= 1) {
            u64 o = __shfl_xor(pk, m, 64);
            pk = (o > pk) ? o : pk;
        }
        if (lane == 0) cand[wave] = pk;
        __syncthreads();
        if (wave == 0) {
            // stage-2: all 64 lanes read cand[lane&15]; reduce within 16-group
            u64 c = cand[lane & 15];
#pragma unroll
            for (int m = 8; m >= 1; m >>= 1) {
                u64 o = __shfl_xor(c, m, 64);
                c = (o > c) ? o : c;
            }
            // lane0: own-winner coords from LDS (always own chunk), store slot
            const int g0 = (int)(0xFFFFFFFFu - (u32)(c & 0xFFFFFFFFull));
            float wx0 = 0.f, wy0 = 0.f, wz0 = 0.f;
            if (lane == 0) {
                const int lw = g0 - base;
                wx0 = P[lw * 3 + 0];
                wy0 = P[lw * 3 + 1];
                wz0 = P[lw * 3 + 2];
                int4v h0, h1;
                h0.x = (int)(u32)(c & 0xFFFFFFFFull);
                h0.y = (int)(u32)(c >> 32);
                h0.z = __float_as_int(wx0);
                h0.w = __float_as_int(wy0);
                h1.x = h0.x;
                h1.y = h0.y;
                h1.z = __float_as_int(wz0);
                h1.w = 0;
                u32* sp = slot_b + ((size_t)s * BPB + j) * 8;
                asm volatile(
                    "global_store_dwordx4 %0, %2, off sc0 sc1\n\t"
                    "global_store_dwordx4 %1, %3, off sc0 sc1"
                    :: "v"(sp), "v"(sp + 4), "v"(h0), "v"(h1) : "memory");
            }
            if (lane < BPB) {
                // poll foreign slots only (own candidate is in-register)
                u64 k = 0;
                float wx = 0.f, wy = 0.f, wz = 0.f;
                if (lane != j) {
                    const u32* pp = slot_b + ((size_t)s * BPB + lane) * 8;
                    int4v a, bb;
                    for (;;) {
                        asm volatile(
                            "global_load_dwordx4 %0, %2, off sc0 sc1\n\t"
                            "global_load_dwordx4 %1, %3, off sc0 sc1\n\t"
                            "s_waitcnt vmcnt(0)"
                            : "=&v"(a), "=&v"(bb)
                            : "v"(pp), "v"(pp + 4) : "memory");
                        if (a.x != 0 && a.x == bb.x && a.y == bb.y) break;
                    }
                    k = ((u64)(u32)a.y << 32) | (u32)a.x;
                    wx = __int_as_float(a.z);
                    wy = __int_as_float(a.w);
                    wz = __int_as_float(bb.z);
                }
                u64 mx = (c > k) ? c : k;        // fold own candidate in
#pragma unroll
                for (int m = 4; m >= 1; m >>= 1) {
                    u64 o = __shfl_xor(mx, m, 64);
                    mx = (o > mx) ? o : mx;
                }
                const int g = (int)(0xFFFFFFFFu - (u32)(mx & 0xFFFFFFFFull));
                const int jw = (g >> 13) & 7;    // owning block of winner
                float sx = __shfl(wx, jw, 64);
                float sy = __shfl(wy, jw, 64);
                float sz = __shfl(wz, jw, 64);
                if (lane == 0) {
                    sel_hist[s] = g;
                    if (jw == j) { qsh[0] = wx0; qsh[1] = wy0; qsh[2] = wz0; }
                    else         { qsh[0] = sx;  qsh[1] = sy;  qsh[2] = sz;  }
                    if (j == 0) out_idx[s] = (float)g;
                }
            }
        }
        __syncthreads();
        qx = qsh[0]; qy = qsh[1]; qz = qsh[2];
    }

    if (j == 0) {
        const int gi = sel_hist[t];
        const float* __restrict__ p = pb + (size_t)gi * 3;
        out_pts[(size_t)t * 3 + 0] = p[0];
        out_pts[(size_t)t * 3 + 1] = p[1];
        out_pts[(size_t)t * 3 + 2] = p[2];
    }
}

// ---------------- R5 fallback: verified slot-store protocol (2 MB ws) -------
__global__ __launch_bounds__(NT) void fps_slots(const float* __restrict__ pts,
                                                float* __restrict__ out,
                                                u64* __restrict__ slots) {
#pragma clang fp contract(off)
    const int bid = blockIdx.x;
    const int b = bid >> 3;
    const int j = bid & 7;
    const int t = threadIdx.x;
    const int base = j * CHUNK;
    const float* __restrict__ pb = pts + (size_t)b * NP * 3;
    float* __restrict__ out_idx = out + (size_t)b * NS;
    float* __restrict__ out_pts = out + (size_t)NB * NS + (size_t)b * NS * 3;
    u64* __restrict__ slot_b = slots + (size_t)b * NS * BPB;

    __shared__ float P[CHUNK * 3];
    __shared__ u64 cand[NT / 64];
    __shared__ int sel_hist[NS];
    __shared__ float qsh[3];

    {
        const float4* __restrict__ src4 = (const float4*)(pb + (size_t)base * 3);
        float4* dst4 = (float4*)P;
#pragma unroll
        for (int k = 0; k < (CHUNK * 3 / 4) / NT; ++k) dst4[t + k * NT] = src4[t + k * NT];
    }
    float md[PPT2];
#pragma unroll
    for (int i = 0; i < PPT2; ++i) md[i] = 1e10f;
    if (t == 0) {
        sel_hist[0] = 0;
        if (j == 0) out_idx[0] = 0.0f;
        qsh[0] = pb[0]; qsh[1] = pb[1]; qsh[2] = pb[2];
    }
    __syncthreads();
    float qx = qsh[0], qy = qsh[1], qz = qsh[2];
    const int wave = t >> 6;
    const int lane = t & 63;
    for (int s = 1; s < NS; ++s) {
        float bestv = -1.0f;
        int besti = 0;
#pragma unroll
        for (int i = 0; i < PPT2; ++i) {
            const int li = t + i * NT;
            const float* __restrict__ p = P + li * 3;
            float dx = p[0] - qx, dy = p[1] - qy, dz = p[2] - qz;
            float d = (dx * dx + dy * dy) + dz * dz;
            float nmd = fminf(md[i], d);
            md[i] = nmd;
            if (nmd > bestv) { bestv = nmd; besti = li; }
        }
        u64 pk = ((u64)__float_as_uint(bestv) << 32) |
                 (u64)(0xFFFFFFFFu - (u32)(base + besti));
#pragma unroll
        for (int m = 32; m >= 1; m >>= 1) {
            u64 o = __shfl_xor(pk, m, 64);
            pk = (o > pk) ? o : pk;
        }
        if (lane == 0) cand[wave] = pk;
        __syncthreads();
        if (wave == 0) {
            u64 c = (lane < 16) ? cand[lane] : 0ull;
#pragma unroll
            for (int m = 8; m >= 1; m >>= 1) {
                u64 o = __shfl_xor(c, m, 64);
                c = (o > c) ? o : c;
            }
            if (lane == 0) {
                __hip_atomic_store(&slot_b[(size_t)s * BPB + j], c,
                                   __ATOMIC_RELAXED, __HIP_MEMORY_SCOPE_AGENT);
            }
            u64 x = 0;
            if (lane < BPB) {
                const u64* sp = &slot_b[(size_t)s * BPB + lane];
                while ((x = __hip_atomic_load(sp, __ATOMIC_RELAXED,
                                              __HIP_MEMORY_SCOPE_AGENT)) == 0ull) {
                    __builtin_amdgcn_s_sleep(1);
                }
            }
#pragma unroll
            for (int m = 4; m >= 1; m >>= 1) {
                u64 o = __shfl_xor(x, m, 64);
                x = (o > x) ? o : x;
            }
            if (lane == 0) {
                int w = (int)(0xFFFFFFFFu - (u32)(x & 0xFFFFFFFFull));
                sel_hist[s] = w;
                const float* __restrict__ q = pb + (size_t)w * 3;
                qsh[0] = q[0]; qsh[1] = q[1]; qsh[2] = q[2];
                if (j == 0) out_idx[s] = (float)w;
            }
        }
        __syncthreads();
        qx = qsh[0]; qy = qsh[1]; qz = qsh[2];
    }
    if (j == 0) {
        const int gi = sel_hist[t];
        const float* __restrict__ p = pb + (size_t)gi * 3;
        out_pts[(size_t)t * 3 + 0] = p[0];
        out_pts[(size_t)t * 3 + 1] = p[1];
        out_pts[(size_t)t * 3 + 2] = p[2];
    }
}

extern "C" void kernel_launch(void* const* d_in, const int* in_sizes, int n_in,
                              void* d_out, int out_size, void* d_ws, size_t ws_size,
                              hipStream_t stream) {
    const float* pts = (const float*)d_in[0];
    float* out = (float*)d_out;
    (void)in_sizes; (void)n_in; (void)out_size;

    const size_t v7_bytes = (size_t)NB * NS * BPB * 32;             // 8 MB
    const size_t slot_bytes = (size_t)NB * NS * BPB * sizeof(u64);  // 2 MB
    if (ws_size >= v7_bytes) {
        u32* slots = (u32*)d_ws;
        hipMemsetAsync(d_ws, 0, v7_bytes, stream);
        void* args[] = {(void*)&pts, (void*)&out, (void*)&slots};
        hipLaunchCooperativeKernel((const void*)fps_v7, dim3(NB * BPB), dim3(NT),
                                   args, 0, stream);
    } else {
        u64* slots = (u64*)d_ws;
        hipMemsetAsync(d_ws, 0, slot_bytes, stream);
        void* args[] = {(void*)&pts, (void*)&out, (void*)&slots};
        hipLaunchCooperativeKernel((const void*)fps_slots, dim3(NB * BPB), dim3(NT),
                                   args, 0, stream);
    }
}